// Round 4
// baseline (12772.108 us; speedup 1.0000x reference)
//
#include <hip/hip_runtime.h>
#include <cstdint>
#include <cstddef>

// ---------------------------------------------------------------------------
// MDHP-LSTM on MI355X.  S=512, B=128, D=256, H=512.
// Output: outputs[S,B,H] ++ h_T[B,H] ++ c_T[B,H].
//
// Persistent kernel, 256 WGs (8 chains x 32 col-WGs); the actor is the WAVE:
// 1024 independent waves, each owning 16 gate-cols = 4 gates x 4 h-cols
// (interleaved n-layout). Round-4 delta vs round-3 (which was structurally
// right but numerically scrambled):
//   * FIX: ds_swizzle BitMode and_mask is 5 bits. Intended src =
//     (lane & 0b10011) | (g<<2)  ->  offsets 0x013/0x093/0x113/0x193.
//     Round-3's 0x033/0x0B3/... decoded to or_mask|=1 (pulled col u|1).
//   * everything else identical: B-frags in 96 VGPRs (no LDS in loop),
//     zero barriers in the step loop, per-wave release flags + __all poll,
//     x A-frags software-pipelined one step ahead.
// ---------------------------------------------------------------------------

typedef __attribute__((ext_vector_type(8))) short short8;
typedef __attribute__((ext_vector_type(4))) float floatx4;

#define SEQ 512
#define BATCH 128
#define DIN 256
#define HID 512
#define KTOT 768
#define NCHAIN 8
#define NCOLW 32

__device__ __forceinline__ short f2bf(float f) {
  union { float f; unsigned u; } v; v.f = f;
  unsigned u = v.u + 0x7fffu + ((v.u >> 16) & 1u);   // RNE
  return (short)(u >> 16);
}
__device__ __forceinline__ float fsig(float x) {
  return 1.f / (1.f + __expf(-x));
}
__device__ __forceinline__ float ftanh(float x) {
  float a = fabsf(x);
  float e = __expf(-2.f * a);
  float r = (1.f - e) / (1.f + e);
  return copysignf(r, x);
}

// ---- prep: GT[n][k] = bf16 of (k<256 ? W_g[k][hc] : U_g[k-256][hc]), n=g*512+hc
__global__ void prep_gt(const float* __restrict__ Wi, const float* __restrict__ Ui,
                        const float* __restrict__ Wf, const float* __restrict__ Uf,
                        const float* __restrict__ Wc, const float* __restrict__ Uc,
                        const float* __restrict__ Wo, const float* __restrict__ Uo,
                        short* __restrict__ GT) {
  int idx = blockIdx.x * 256 + threadIdx.x;
  if (idx >= 2048 * KTOT) return;
  int n = idx / KTOT, k = idx % KTOT;
  int g = n >> 9, hc = n & 511;
  const float* W; const float* U;
  if (g == 0)      { W = Wi; U = Ui; }
  else if (g == 1) { W = Wf; U = Uf; }
  else if (g == 2) { W = Wc; U = Uc; }
  else             { W = Wo; U = Uo; }
  float v = (k < DIN) ? W[k * HID + hc] : U[(k - DIN) * HID + hc];
  GT[idx] = f2bf(v);
}

// ---- prep: x -> bf16 (4 elems/thread)
__global__ void prep_xb(const float* __restrict__ x, short* __restrict__ xb) {
  int idx = blockIdx.x * 256 + threadIdx.x;           // 4,194,304
  float4 v = ((const float4*)x)[idx];
  short4 o; o.x = f2bf(v.x); o.y = f2bf(v.y); o.z = f2bf(v.z); o.w = f2bf(v.w);
  ((short4*)xb)[idx] = o;
}

// ---- prep: h0 -> hbuf slot 0 (bf16)
__global__ void prep_h0(const float* __restrict__ h0, short* __restrict__ hbuf) {
  int idx = blockIdx.x * 256 + threadIdx.x;           // 65536
  hbuf[idx] = f2bf(h0[idx]);
}

// ---- prep: mdhp[b][h] = tanh(alpha@A - (beta*tspan)@B + theta@C)  (fp32)
__global__ void prep_mdhp(const float* __restrict__ alpha, const float* __restrict__ beta,
                          const float* __restrict__ theta, const float* __restrict__ tspan,
                          const float* __restrict__ A, const float* __restrict__ Bm,
                          const float* __restrict__ C, float* __restrict__ mdhp) {
  int idx = blockIdx.x * 256 + threadIdx.x;           // 65536
  int b = idx >> 9, h = idx & 511;
  float ts = tspan[b];
  float acc = 0.f;
  for (int k = 0; k < 256; ++k)
    acc += alpha[b * 256 + k] * A[k * HID + h] - ts * beta[b * 256 + k] * Bm[k * HID + h];
  for (int k = 0; k < 16; ++k)
    acc += theta[b * 16 + k] * C[k * HID + h];
  mdhp[idx] = tanhf(acc);
}

__global__ void zero_flags(int* __restrict__ flags) {
  int idx = blockIdx.x * 256 + threadIdx.x;           // 524,288
  flags[idx] = 0;
}

// ---- the persistent recurrence kernel --------------------------------------
__global__ __launch_bounds__(256, 1) void lstm_persist(
    const short* __restrict__ xb, const float* __restrict__ c0,
    const float* __restrict__ bi, const float* __restrict__ bf_,
    const float* __restrict__ bc, const float* __restrict__ bo,
    const short* __restrict__ GT, const float* __restrict__ mdhp,
    int* flags, short* hbuf, float* out) {
  const int tid   = threadIdx.x;
  const int wg    = blockIdx.x;
  const int chain = wg & 7;        // XCD-local under round-robin (perf only)
  const int j     = wg >> 3;       // 0..31 column group (16 h-cols)
  const int w     = tid >> 6;      // wave 0..3: h-cols j*16+w*4 .. +4
  const int lane  = tid & 63;
  const int q     = lane >> 4;     // quad
  const int c     = lane & 15;     // n-col within tile
  const int g     = c >> 2;        // gate of this lane's n-col
  const int u     = c & 3;         // local h-col of this lane's n-col
  const int mr    = c;             // A-operand row (batch row within chain)
  const int bglob = (chain << 4) + mr;
  const int jcol  = (j << 4) + (w << 2) + u;            // epilogue h-col
  const int gtrow = (g << 9) + jcol;                    // GT row for n-col
  const bool owner = (lane & 12) == 0;                  // 16 lanes store
  const int  slot  = (j << 2) + w;                      // flag slot 0..127

  // ---- loop-invariant register state: 24 B-frags = 96 VGPRs, no LDS
  short8 breg[24];
#pragma unroll
  for (int kk = 0; kk < 24; ++kk)
    breg[kk] = *(const short8*)(GT + (size_t)gtrow * KTOT + kk * 32 + q * 8);

  const float biasv0 = bi[jcol], biasv1 = bf_[jcol],
              biasv2 = bc[jcol], biasv3 = bo[jcol];
  float carr[4], md[4];
#pragma unroll
  for (int i = 0; i < 4; ++i) {
    int row = (chain << 4) + (q << 2) + i;
    carr[i] = c0[row * HID + jcol];
    md[i]   = mdhp[row * HID + jcol];
  }

  // ---- prefetch x A-frags for t=0
  short8 xaf[8];
  {
    const short* xr = xb + (size_t)bglob * DIN + q * 8;
#pragma unroll
    for (int kk = 0; kk < 8; ++kk) xaf[kk] = *(const short8*)(xr + kk * 32);
  }

  for (int t = 0; t < SEQ; ++t) {
    // ---- x @ W (h-independent: overlaps the producers' tail)
    floatx4 accA = {0.f, 0.f, 0.f, 0.f};
#pragma unroll
    for (int kk = 0; kk < 8; ++kk)
      accA = __builtin_amdgcn_mfma_f32_16x16x32_bf16(xaf[kk], breg[kk], accA, 0, 0, 0);

    // ---- wait for all 128 producer-waves of this chain @ t-1
    if (t > 0) {
      const unsigned long long* fp = (const unsigned long long*)
          (flags + ((size_t)chain * SEQ + (t - 1)) * 128) + lane;
      for (;;) {
        unsigned long long v = __hip_atomic_load(fp, __ATOMIC_RELAXED,
                                                 __HIP_MEMORY_SCOPE_AGENT);
        int ok = ((unsigned)v != 0u) && ((unsigned)(v >> 32) != 0u);
        if (__all(ok)) break;
        __builtin_amdgcn_s_sleep(1);
      }
      __builtin_amdgcn_fence(__ATOMIC_ACQUIRE, "agent");
    }

    // ---- h A-frags (bf16 ring buffer, slot t = h_{t-1})
    const short* hr = hbuf + ((size_t)t * BATCH + bglob) * HID + q * 8;
    short8 haf[16];
#pragma unroll
    for (int kk = 0; kk < 16; ++kk) haf[kk] = *(const short8*)(hr + kk * 32);

    floatx4 accB = {0.f, 0.f, 0.f, 0.f}, accC = {0.f, 0.f, 0.f, 0.f};
#pragma unroll
    for (int kk = 0; kk < 8; ++kk)
      accB = __builtin_amdgcn_mfma_f32_16x16x32_bf16(haf[kk], breg[8 + kk], accB, 0, 0, 0);
#pragma unroll
    for (int kk = 8; kk < 16; ++kk)
      accC = __builtin_amdgcn_mfma_f32_16x16x32_bf16(haf[kk], breg[8 + kk], accC, 0, 0, 0);

    // ---- in-wave gate exchange + epilogue
    // lane holds D[row=q*4+i][n-col=c], c = g*4+u. Gate g' for (row,u) lives
    // in lane (lane & 0b10011) | (g'<<2); ds_swizzle BitMode offset =
    // (or<<5)|and with and=0x13, or=g'*4 -> 0x013/0x093/0x113/0x193.
    float hv[4], cnv[4];
#pragma unroll
    for (int i = 0; i < 4; ++i) {
      float d = accA[i] + accB[i] + accC[i];
      int di = __builtin_bit_cast(int, d);
      float gi = __builtin_bit_cast(float, __builtin_amdgcn_ds_swizzle(di, 0x013)) + biasv0;
      float gf = __builtin_bit_cast(float, __builtin_amdgcn_ds_swizzle(di, 0x093)) + biasv1;
      float gc = __builtin_bit_cast(float, __builtin_amdgcn_ds_swizzle(di, 0x113)) + biasv2;
      float go = __builtin_bit_cast(float, __builtin_amdgcn_ds_swizzle(di, 0x193)) + biasv3;
      float it = fsig(gi), ft = fsig(gf), ot = fsig(go);
      float ch = ftanh(gc);
      float cn = md[i] * (ft * carr[i] + it * ch);
      carr[i] = cn;
      cnv[i]  = cn;
      hv[i]   = ot * ftanh(cn);
    }

    // ---- h handoff (bf16, agent write-through), then release flag
    if (owner) {
#pragma unroll
      for (int i = 0; i < 4; ++i) {
        size_t hidx = ((size_t)(t + 1) * BATCH + (chain << 4) + (q << 2) + i) * HID + jcol;
        __hip_atomic_store(&hbuf[hidx], f2bf(hv[i]), __ATOMIC_RELAXED,
                           __HIP_MEMORY_SCOPE_AGENT);
      }
    }
    if (lane == 0)
      __hip_atomic_store(&flags[((size_t)chain * SEQ + t) * 128 + slot], 1,
                         __ATOMIC_RELEASE, __HIP_MEMORY_SCOPE_AGENT);

    // ---- fp32 outputs (nobody reads them: after the flag, off critical path)
    if (owner) {
#pragma unroll
      for (int i = 0; i < 4; ++i) {
        int row = (chain << 4) + (q << 2) + i;
        out[((size_t)t * BATCH + row) * HID + jcol] = hv[i];
      }
      if (t == SEQ - 1) {
        size_t base = (size_t)SEQ * BATCH * HID;
#pragma unroll
        for (int i = 0; i < 4; ++i) {
          int row = (chain << 4) + (q << 2) + i;
          out[base + row * HID + jcol] = hv[i];                 // h_T
          out[base + BATCH * HID + row * HID + jcol] = cnv[i];  // c_T
        }
      }
    }

    // ---- prefetch x A-frags for t+1 (lands during next poll + h-load)
    int tn = (t + 1 < SEQ) ? t + 1 : SEQ - 1;
    const short* xr = xb + ((size_t)tn * BATCH + bglob) * DIN + q * 8;
#pragma unroll
    for (int kk = 0; kk < 8; ++kk) xaf[kk] = *(const short8*)(xr + kk * 32);
  }
}

// ---------------------------------------------------------------------------
extern "C" void kernel_launch(void* const* d_in, const int* in_sizes, int n_in,
                              void* d_out, int out_size, void* d_ws, size_t ws_size,
                              hipStream_t stream) {
  const float* x     = (const float*)d_in[0];
  const float* h0    = (const float*)d_in[1];
  const float* c0    = (const float*)d_in[2];
  const float* alpha = (const float*)d_in[3];
  const float* beta  = (const float*)d_in[4];
  const float* theta = (const float*)d_in[5];
  const float* tspan = (const float*)d_in[6];
  const float* Amd   = (const float*)d_in[7];
  const float* Bmd   = (const float*)d_in[8];
  const float* Cmd   = (const float*)d_in[9];
  const float* Wi = (const float*)d_in[10]; const float* Ui = (const float*)d_in[11];
  const float* bi = (const float*)d_in[12];
  const float* Wf = (const float*)d_in[13]; const float* Uf = (const float*)d_in[14];
  const float* bf_ = (const float*)d_in[15];
  const float* Wc = (const float*)d_in[16]; const float* Uc = (const float*)d_in[17];
  const float* bc = (const float*)d_in[18];
  const float* Wo = (const float*)d_in[19]; const float* Uo = (const float*)d_in[20];
  const float* bo = (const float*)d_in[21];

  float* out = (float*)d_out;
  char* ws = (char*)d_ws;
  // ws layout (bytes):
  size_t off = 0;
  short* GT    = (short*)(ws + off); off += (size_t)2048 * KTOT * 2;   //  3,145,728
  float* mdhp  = (float*)(ws + off); off += (size_t)65536 * 4;         //    262,144
  int*   flags = (int*)(ws + off);   off += (size_t)NCHAIN * SEQ * 128 * 4; // 2,097,152
  short* xb    = (short*)(ws + off); off += (size_t)SEQ * BATCH * DIN * 2;  // 33,554,432
  short* hbuf  = (short*)(ws + off);                                   // 513*128*512*2

  zero_flags<<<2048, 256, 0, stream>>>(flags);
  prep_gt<<<(2048 * KTOT + 255) / 256, 256, 0, stream>>>(Wi, Ui, Wf, Uf, Wc, Uc, Wo, Uo, GT);
  prep_xb<<<16384, 256, 0, stream>>>(x, xb);
  prep_h0<<<256, 256, 0, stream>>>(h0, hbuf);
  prep_mdhp<<<256, 256, 0, stream>>>(alpha, beta, theta, tspan, Amd, Bmd, Cmd, mdhp);
  lstm_persist<<<NCHAIN * NCOLW, 256, 0, stream>>>(xb, c0, bi, bf_, bc, bo,
                                                   GT, mdhp, flags, hbuf, out);
}